// Round 6
// baseline (575.380 us; speedup 1.0000x reference)
//
#include <hip/hip_runtime.h>
#include <hip/hip_bf16.h>

#define B_ 256
#define T_ 512
#define I_ 256
#define H_ 256

typedef float  f32x4  __attribute__((ext_vector_type(4)));
typedef short  bf16x8 __attribute__((ext_vector_type(8)));
typedef short  s16x4  __attribute__((ext_vector_type(4)));
typedef _Float16 f16x2 __attribute__((ext_vector_type(2)));
typedef _Float16 f16x4 __attribute__((ext_vector_type(4)));
typedef _Float16 f16x8 __attribute__((ext_vector_type(8)));

// f32 -> bf16 round-to-nearest-even
static __device__ __forceinline__ short f2bf(float f) {
  unsigned u = __builtin_bit_cast(unsigned, f);
  u += 0x7FFFu + ((u >> 16) & 1u);
  return (short)(u >> 16);
}

// ---------------- kernel 0: W_x f32 -> bf16 (into ws) ----------------
__global__ __launch_bounds__(256) void wx_to_bf16(const float* __restrict__ wx,
                                                  short* __restrict__ wb) {
  int i = blockIdx.x * 256 + threadIdx.x;           // each handles 4 elems
  f32x4 v = ((const f32x4*)wx)[i];
  s16x4 o;
  o[0] = f2bf(v[0]); o[1] = f2bf(v[1]); o[2] = f2bf(v[2]); o[3] = f2bf(v[3]);
  ((s16x4*)wb)[i] = o;
}

// ---------------- kernel 1: Xp = x @ W_x^T  (MFMA bf16) ----------------
// x: [131072, 256] f32 row-major; W: [h, i] (h*256+i); Xp: [131072, 256] f32.
// Block = 256 thr (4 waves). Wave: M=16 rows, N=256 (16 n-tiles), K=256.
template <bool PRE>
__global__ __launch_bounds__(256) void xproj(const float* __restrict__ x,
                                             const float* __restrict__ wxf,
                                             const short* __restrict__ wxb,
                                             float* __restrict__ xp) {
  const int l  = threadIdx.x & 63;
  const int w  = threadIdx.x >> 6;
  const int m0 = (blockIdx.x * 4 + w) * 16;
  const int lr = l & 15;          // row within A-frag / col within D
  const int g  = l >> 4;          // k-group
  f32x4 acc[16];
#pragma unroll
  for (int nt = 0; nt < 16; ++nt) acc[nt] = f32x4{0.f, 0.f, 0.f, 0.f};

  for (int kk = 0; kk < 8; ++kk) {
    const int k = kk * 32 + g * 8;
    // A fragment: lane holds x[m0+lr][k..k+8)
    const f32x4* xa = (const f32x4*)(x + (size_t)(m0 + lr) * I_ + k);
    f32x4 a0 = xa[0], a1 = xa[1];
    bf16x8 af;
    af[0] = f2bf(a0[0]); af[1] = f2bf(a0[1]); af[2] = f2bf(a0[2]); af[3] = f2bf(a0[3]);
    af[4] = f2bf(a1[0]); af[5] = f2bf(a1[1]); af[6] = f2bf(a1[2]); af[7] = f2bf(a1[3]);
#pragma unroll
    for (int nt = 0; nt < 16; ++nt) {
      const int n = nt * 16 + lr;
      bf16x8 bf;
      if (PRE) {
        bf = *(const bf16x8*)(wxb + (size_t)n * I_ + k);
      } else {
        const f32x4* wa = (const f32x4*)(wxf + (size_t)n * I_ + k);
        f32x4 b0 = wa[0], b1 = wa[1];
        bf[0] = f2bf(b0[0]); bf[1] = f2bf(b0[1]); bf[2] = f2bf(b0[2]); bf[3] = f2bf(b0[3]);
        bf[4] = f2bf(b1[0]); bf[5] = f2bf(b1[1]); bf[6] = f2bf(b1[2]); bf[7] = f2bf(b1[3]);
      }
      acc[nt] = __builtin_amdgcn_mfma_f32_16x16x32_bf16(af, bf, acc[nt], 0, 0, 0);
    }
  }
  // D layout (measured): row = (l>>4)*4 + r, col = l&15
#pragma unroll
  for (int nt = 0; nt < 16; ++nt) {
#pragma unroll
    for (int r = 0; r < 4; ++r) {
      const int rr = m0 + g * 4 + r;
      xp[(size_t)rr * H_ + nt * 16 + lr] = acc[nt][r];
    }
  }
}

// ---------------- kernel 2: recurrence v4 — MFMA, weights stationary ----------------
// One block per batch row, 512 threads (8 waves). Per step: y = W_h @ h as a
// 16x16x32 f16 MFMA with batch padded to N=16 (only col 0 real).
//   A-frag (stationary, VGPRs): lane holds W_h[h0 + tile*16 + (l&15)][kc*32 + (l>>4)*8 + j]
//   B-frag: lanes l&15==0 read h[kc*32 + (l>>4)*8 ..+8) from LDS (64B/wave, conflict-free);
//           all other lanes contribute zero frags.
//   D: row=(l>>4)*4+r = h_out, col=l&15 = batch -> lanes 0/16/32/48 hold 4 real outputs.
// Wave w owns h_out [w*32, w*32+32) as 2 tiles. One barrier/step, double-buffered h.
__global__ __launch_bounds__(512) void rnn_rec4(const float* __restrict__ whf,
                                                const float* __restrict__ bias_g,
                                                float* __restrict__ io) {
  __shared__ __align__(16) _Float16 hb[2][H_];      // 512B each
  const int tid = threadIdx.x;
  const int l   = tid & 63;
  const int w   = tid >> 6;
  const int lr  = l & 15;
  const int g   = l >> 4;
  const int h0  = w * 32;
  const bool act = (lr == 0);
  const size_t base = (size_t)blockIdx.x * T_ * H_;

  // stationary weights: wA[tile*8+kc], all indices compile-time in the loops
  f16x8 wA[16];
#pragma unroll
  for (int tile = 0; tile < 2; ++tile) {
#pragma unroll
    for (int kc = 0; kc < 8; ++kc) {
      const float* p = whf + (size_t)(h0 + tile * 16 + lr) * H_ + kc * 32 + g * 8;
      f32x4 v0 = *(const f32x4*)p;
      f32x4 v1 = *(const f32x4*)(p + 4);
      wA[tile * 8 + kc] = f16x8{(_Float16)v0[0], (_Float16)v0[1], (_Float16)v0[2], (_Float16)v0[3],
                                (_Float16)v1[0], (_Float16)v1[1], (_Float16)v1[2], (_Float16)v1[3]};
    }
  }

  // bias (rows g*4..g*4+3 of each tile); unguarded loads are fine (valid addrs)
  const f32x4 biasA = *(const f32x4*)(bias_g + h0 + g * 4);
  const f32x4 biasB = *(const f32x4*)(bias_g + h0 + 16 + g * 4);

  if (tid < 128) ((f16x2*)hb[0])[tid] = f16x2{(_Float16)0.f, (_Float16)0.f};

  // xp for t=0 (cur) and prefetch reg (next)
  f32x4 xA_c = *(const f32x4*)(io + base + h0 + g * 4);
  f32x4 xB_c = *(const f32x4*)(io + base + h0 + 16 + g * 4);
  __syncthreads();

  for (int t = 0; t < T_; ++t) {
    // prefetch xp[t+1] (consumed next step; latency hidden under MFMA+epilogue)
    f32x4 xA_n = {}, xB_n = {};
    if (t + 1 < T_) {
      const float* q = io + base + (size_t)(t + 1) * H_ + h0;
      xA_n = *(const f32x4*)(q + g * 4);
      xB_n = *(const f32x4*)(q + 16 + g * 4);
    }

    f32x4 accA = f32x4{0.f, 0.f, 0.f, 0.f};
    f32x4 accB = f32x4{0.f, 0.f, 0.f, 0.f};
    const f16x8* hp = (const f16x8*)hb[t & 1];
    const f16x8 zf = f16x8{(_Float16)0.f, (_Float16)0.f, (_Float16)0.f, (_Float16)0.f,
                           (_Float16)0.f, (_Float16)0.f, (_Float16)0.f, (_Float16)0.f};
#pragma unroll
    for (int kc = 0; kc < 8; ++kc) {
      f16x8 bv = zf;
      if (act) bv = hp[kc * 4 + g];                 // 4 lanes, 64B, conflict-free
      accA = __builtin_amdgcn_mfma_f32_16x16x32_f16(wA[kc],     bv, accA, 0, 0, 0);
      accB = __builtin_amdgcn_mfma_f32_16x16x32_f16(wA[8 + kc], bv, accB, 0, 0, 0);
    }

    if (act) {
      f32x4 yA = accA + xA_c + biasA;
      f32x4 yB = accB + xB_c + biasB;
      f32x4 hA, hB;
#pragma unroll
      for (int j = 0; j < 4; ++j) {
        float eA = __expf(2.f * yA[j]);
        hA[j] = 1.f - 2.f * __builtin_amdgcn_rcpf(1.f + eA);   // tanh
        float eB = __expf(2.f * yB[j]);
        hB[j] = 1.f - 2.f * __builtin_amdgcn_rcpf(1.f + eB);
      }
      float* o = io + base + (size_t)t * H_ + h0;
      *(f32x4*)(o + g * 4)      = hA;
      *(f32x4*)(o + 16 + g * 4) = hB;
      _Float16* hn = hb[(t + 1) & 1];
      *(f16x4*)(hn + h0 + g * 4)      = f16x4{(_Float16)hA[0], (_Float16)hA[1], (_Float16)hA[2], (_Float16)hA[3]};
      *(f16x4*)(hn + h0 + 16 + g * 4) = f16x4{(_Float16)hB[0], (_Float16)hB[1], (_Float16)hB[2], (_Float16)hB[3]};
    }
    __syncthreads();                                // order hb write vs next read
    xA_c = xA_n;
    xB_c = xB_n;
  }
}

extern "C" void kernel_launch(void* const* d_in, const int* in_sizes, int n_in,
                              void* d_out, int out_size, void* d_ws, size_t ws_size,
                              hipStream_t stream) {
  const float* x  = (const float*)d_in[0];
  const float* wx = (const float*)d_in[1];
  const float* wh = (const float*)d_in[2];
  const float* b  = (const float*)d_in[3];
  float* out = (float*)d_out;

  const size_t wb_bytes = (size_t)I_ * H_ * sizeof(short);
  if (ws_size >= wb_bytes) {
    short* wb = (short*)d_ws;
    wx_to_bf16<<<64, 256, 0, stream>>>(wx, wb);
    xproj<true><<<2048, 256, 0, stream>>>(x, wx, wb, out);
  } else {
    xproj<false><<<2048, 256, 0, stream>>>(x, wx, nullptr, out);
  }
  rnn_rec4<<<B_, 512, 0, stream>>>(wh, b, out);
}

// Round 7
// 532.612 us; speedup vs baseline: 1.0803x; 1.0803x over previous
//
#include <hip/hip_runtime.h>
#include <hip/hip_bf16.h>

#define B_ 256
#define T_ 512
#define I_ 256
#define H_ 256
#define CHUNK 64

typedef float  f32x4  __attribute__((ext_vector_type(4)));
typedef short  bf16x8 __attribute__((ext_vector_type(8)));
typedef short  s16x4  __attribute__((ext_vector_type(4)));
typedef _Float16 f16x2 __attribute__((ext_vector_type(2)));
typedef _Float16 f16x4 __attribute__((ext_vector_type(4)));
typedef _Float16 f16x8 __attribute__((ext_vector_type(8)));

// f32 -> bf16 round-to-nearest-even
static __device__ __forceinline__ short f2bf(float f) {
  unsigned u = __builtin_bit_cast(unsigned, f);
  u += 0x7FFFu + ((u >> 16) & 1u);
  return (short)(u >> 16);
}

// ---------------- kernel 0: W_x f32 -> bf16 (into ws) ----------------
__global__ __launch_bounds__(256) void wx_to_bf16(const float* __restrict__ wx,
                                                  short* __restrict__ wb) {
  int i = blockIdx.x * 256 + threadIdx.x;           // each handles 4 elems
  f32x4 v = ((const f32x4*)wx)[i];
  s16x4 o;
  o[0] = f2bf(v[0]); o[1] = f2bf(v[1]); o[2] = f2bf(v[2]); o[3] = f2bf(v[3]);
  ((s16x4*)wb)[i] = o;
}

// ---------------- kernel 1: Xp = x @ W_x^T  (MFMA bf16) ----------------
template <bool PRE>
__global__ __launch_bounds__(256) void xproj(const float* __restrict__ x,
                                             const float* __restrict__ wxf,
                                             const short* __restrict__ wxb,
                                             float* __restrict__ xp) {
  const int l  = threadIdx.x & 63;
  const int w  = threadIdx.x >> 6;
  const int m0 = (blockIdx.x * 4 + w) * 16;
  const int lr = l & 15;          // row within A-frag / col within D
  const int g  = l >> 4;          // k-group
  f32x4 acc[16];
#pragma unroll
  for (int nt = 0; nt < 16; ++nt) acc[nt] = f32x4{0.f, 0.f, 0.f, 0.f};

  for (int kk = 0; kk < 8; ++kk) {
    const int k = kk * 32 + g * 8;
    const f32x4* xa = (const f32x4*)(x + (size_t)(m0 + lr) * I_ + k);
    f32x4 a0 = xa[0], a1 = xa[1];
    bf16x8 af;
    af[0] = f2bf(a0[0]); af[1] = f2bf(a0[1]); af[2] = f2bf(a0[2]); af[3] = f2bf(a0[3]);
    af[4] = f2bf(a1[0]); af[5] = f2bf(a1[1]); af[6] = f2bf(a1[2]); af[7] = f2bf(a1[3]);
#pragma unroll
    for (int nt = 0; nt < 16; ++nt) {
      const int n = nt * 16 + lr;
      bf16x8 bf;
      if (PRE) {
        bf = *(const bf16x8*)(wxb + (size_t)n * I_ + k);
      } else {
        const f32x4* wa = (const f32x4*)(wxf + (size_t)n * I_ + k);
        f32x4 b0 = wa[0], b1 = wa[1];
        bf[0] = f2bf(b0[0]); bf[1] = f2bf(b0[1]); bf[2] = f2bf(b0[2]); bf[3] = f2bf(b0[3]);
        bf[4] = f2bf(b1[0]); bf[5] = f2bf(b1[1]); bf[6] = f2bf(b1[2]); bf[7] = f2bf(b1[3]);
      }
      acc[nt] = __builtin_amdgcn_mfma_f32_16x16x32_bf16(af, bf, acc[nt], 0, 0, 0);
    }
  }
#pragma unroll
  for (int nt = 0; nt < 16; ++nt) {
#pragma unroll
    for (int r = 0; r < 4; ++r) {
      const int rr = m0 + g * 4 + r;
      xp[(size_t)rr * H_ + nt * 16 + lr] = acc[nt][r];
    }
  }
}

// ---------------- kernel 2: recurrence v5 — MFMA + LDS-staged xp/out ----------------
// One block per batch row, 512 threads (8 waves). Super-steps of CHUNK=64:
//   bulk-load 64 steps of xp into LDS -> 64 barrier-steps touching ONLY LDS ->
//   bulk-flush 64 steps of h to global. This removes HBM latency from the
//   per-step critical path (the compiler's s_barrier drains vmcnt(0) — any
//   global op inside the step loop serializes at HBM latency every step).
// MFMA trick: ALL lanes read the same broadcast h chunk for the B-frag, so
// every column of B equals h and every D column is the correct y — no zero
// padding, no exec masking, no cndmask (v4's VALU bloat).
__global__ __launch_bounds__(512) void rnn_rec5(const float* __restrict__ whf,
                                                const float* __restrict__ bias_g,
                                                float* __restrict__ io) {
  __shared__ __align__(16) float    xps[CHUNK][H_];   // 64KB
  __shared__ __align__(16) float    outs[CHUNK][H_];  // 64KB
  __shared__ __align__(16) _Float16 hb[2][H_];        // 1KB
  const int tid = threadIdx.x;
  const int l   = tid & 63;
  const int w   = tid >> 6;
  const int lr  = l & 15;
  const int g   = l >> 4;
  const int h0  = w * 32;
  const size_t base = (size_t)blockIdx.x * T_ * H_;

  // stationary weights (loaded once): wA[tile*8+kc], lane holds
  // W_h[h0 + tile*16 + lr][kc*32 + g*8 .. +8) as f16x8
  f16x8 wA[16];
#pragma unroll
  for (int tile = 0; tile < 2; ++tile) {
#pragma unroll
    for (int kc = 0; kc < 8; ++kc) {
      const float* p = whf + (size_t)(h0 + tile * 16 + lr) * H_ + kc * 32 + g * 8;
      f32x4 v0 = *(const f32x4*)p;
      f32x4 v1 = *(const f32x4*)(p + 4);
      wA[tile * 8 + kc] = f16x8{(_Float16)v0[0], (_Float16)v0[1], (_Float16)v0[2], (_Float16)v0[3],
                                (_Float16)v1[0], (_Float16)v1[1], (_Float16)v1[2], (_Float16)v1[3]};
    }
  }
  const f32x4 biasA = *(const f32x4*)(bias_g + h0 + g * 4);
  const f32x4 biasB = *(const f32x4*)(bias_g + h0 + 16 + g * 4);

  if (tid < 128) ((f16x2*)hb[0])[tid] = f16x2{(_Float16)0.f, (_Float16)0.f};

  int cur = 0;
  for (int t0 = 0; t0 < T_; t0 += CHUNK) {
    // ---- bulk load xp[t0 .. t0+CHUNK) into LDS (coalesced b128) ----
    {
      const f32x4* src = (const f32x4*)(io + base + (size_t)t0 * H_);
      f32x4* dst = (f32x4*)xps;
#pragma unroll
      for (int i = 0; i < (CHUNK * H_ / 4) / 512; ++i)
        dst[i * 512 + tid] = src[i * 512 + tid];
    }
    __syncthreads();                                  // xps ready (drains loads once/chunk)

#pragma unroll 1
    for (int s = 0; s < CHUNK; ++s) {
      f32x4 xA = *(const f32x4*)&xps[s][h0 + g * 4];
      f32x4 xB = *(const f32x4*)&xps[s][h0 + 16 + g * 4];

      f32x4 accA0 = {}, accA1 = {}, accB0 = {}, accB1 = {};
      const f16x8* hp = (const f16x8*)hb[cur];
#pragma unroll
      for (int kc = 0; kc < 8; kc += 2) {
        f16x8 bv0 = hp[kc * 4 + g];                   // broadcast: 4 distinct addrs/wave
        f16x8 bv1 = hp[(kc + 1) * 4 + g];
        accA0 = __builtin_amdgcn_mfma_f32_16x16x32_f16(wA[kc],         bv0, accA0, 0, 0, 0);
        accB0 = __builtin_amdgcn_mfma_f32_16x16x32_f16(wA[8 + kc],     bv0, accB0, 0, 0, 0);
        accA1 = __builtin_amdgcn_mfma_f32_16x16x32_f16(wA[kc + 1],     bv1, accA1, 0, 0, 0);
        accB1 = __builtin_amdgcn_mfma_f32_16x16x32_f16(wA[8 + kc + 1], bv1, accB1, 0, 0, 0);
      }

      f32x4 yA = (accA0 + accA1) + xA + biasA;        // every col-lane holds the same y
      f32x4 yB = (accB0 + accB1) + xB + biasB;
      f32x4 hA, hB;
#pragma unroll
      for (int j = 0; j < 4; ++j) {
        float eA = __expf(2.f * yA[j]);
        hA[j] = 1.f - 2.f * __builtin_amdgcn_rcpf(1.f + eA);   // tanh
        float eB = __expf(2.f * yB[j]);
        hB[j] = 1.f - 2.f * __builtin_amdgcn_rcpf(1.f + eB);
      }
      if (lr == 0) {                                  // one lane per g-group writes
        *(f32x4*)&outs[s][h0 + g * 4]      = hA;
        *(f32x4*)&outs[s][h0 + 16 + g * 4] = hB;
        _Float16* hn = hb[cur ^ 1];
        *(f16x4*)(hn + h0 + g * 4)      = f16x4{(_Float16)hA[0], (_Float16)hA[1], (_Float16)hA[2], (_Float16)hA[3]};
        *(f16x4*)(hn + h0 + 16 + g * 4) = f16x4{(_Float16)hB[0], (_Float16)hB[1], (_Float16)hB[2], (_Float16)hB[3]};
      }
      __syncthreads();                                // LDS-only drain (fast)
      cur ^= 1;
    }

    // ---- bulk flush outs -> io (stores drain at next chunk's barrier) ----
    {
      const f32x4* src = (const f32x4*)outs;
      f32x4* dst = (f32x4*)(io + base + (size_t)t0 * H_);
#pragma unroll
      for (int i = 0; i < (CHUNK * H_ / 4) / 512; ++i) {
        f32x4 v = src[i * 512 + tid];
        dst[i * 512 + tid] = v;
      }
    }
    __syncthreads();                                  // outs reads done before next chunk reuses
  }
}

extern "C" void kernel_launch(void* const* d_in, const int* in_sizes, int n_in,
                              void* d_out, int out_size, void* d_ws, size_t ws_size,
                              hipStream_t stream) {
  const float* x  = (const float*)d_in[0];
  const float* wx = (const float*)d_in[1];
  const float* wh = (const float*)d_in[2];
  const float* b  = (const float*)d_in[3];
  float* out = (float*)d_out;

  const size_t wb_bytes = (size_t)I_ * H_ * sizeof(short);
  if (ws_size >= wb_bytes) {
    short* wb = (short*)d_ws;
    wx_to_bf16<<<64, 256, 0, stream>>>(wx, wb);
    xproj<true><<<2048, 256, 0, stream>>>(x, wx, wb, out);
  } else {
    xproj<false><<<2048, 256, 0, stream>>>(x, wx, nullptr, out);
  }
  rnn_rec5<<<B_, 512, 0, stream>>>(wh, b, out);
}

// Round 8
// 368.949 us; speedup vs baseline: 1.5595x; 1.4436x over previous
//
#include <hip/hip_runtime.h>

#define B_ 256
#define T_ 512
#define I_ 256
#define H_ 256
#define CHUNK 64

typedef float    f32x4 __attribute__((ext_vector_type(4)));
typedef _Float16 f16x2 __attribute__((ext_vector_type(2)));
typedef _Float16 f16x8 __attribute__((ext_vector_type(8)));

static __device__ __forceinline__ f16x8 cvt8(f32x4 a, f32x4 b) {
  return f16x8{(_Float16)a[0], (_Float16)a[1], (_Float16)a[2], (_Float16)a[3],
               (_Float16)b[0], (_Float16)b[1], (_Float16)b[2], (_Float16)b[3]};
}

// ---------------- fused RNN: xproj chunk + recurrence, one block per batch row ----------------
// 512 threads (8 waves). Wave w owns output columns [w*32, w*32+32).
// Transposed MFMA: y^T = h^T @ W^T -> A = h (broadcast to all 16 rows), B = stationary
// weight frags in VGPRs. D col = h-index (lr), every D row = y -> epilogue reads reg 0
// only: 2 scalar tanh per wave-step (vs 16x-redundant epilogue of the old layout).
// Per chunk of 64 steps: (1) compute xp = x@Wx^T + b straight from global x into LDS
// (A-rows = 16 real t-steps, fully coalesced 16B/lane global reads, x read exactly once);
// (2) 64 LDS-only recurrence steps; (3) bulk-flush outputs. Global ops never sit on the
// per-step barrier critical path.
__global__ __launch_bounds__(512) void rnn_fused(const float* __restrict__ x,
                                                 const float* __restrict__ wxf,
                                                 const float* __restrict__ whf,
                                                 const float* __restrict__ bias_g,
                                                 float* __restrict__ io) {
  __shared__ __align__(16) float    xps[CHUNK][H_];   // 64KB: xp + bias for current chunk
  __shared__ __align__(16) float    outs[CHUNK][H_];  // 64KB: staged h outputs
  __shared__ __align__(16) _Float16 hb[2][H_];        // 1KB: double-buffered h state (f16)

  const int tid = threadIdx.x;
  const int l   = tid & 63;
  const int w   = tid >> 6;
  const int lr  = l & 15;
  const int g   = l >> 4;
  const int h0  = w * 32;
  const size_t base = (size_t)blockIdx.x * (size_t)(T_ * H_);

  // Stationary B-fragments (loaded once, held in VGPRs):
  //   frag[tile*8+kc]: lane holds M[h0 + tile*16 + lr][kc*32 + g*8 .. +8) as f16x8
  f16x8 wB[16];   // W_h  (recurrence)
  f16x8 xB[16];   // W_x  (x-projection)
#pragma unroll
  for (int tile = 0; tile < 2; ++tile) {
#pragma unroll
    for (int kc = 0; kc < 8; ++kc) {
      const float* ph = whf + (size_t)(h0 + tile * 16 + lr) * H_ + kc * 32 + g * 8;
      wB[tile * 8 + kc] = cvt8(*(const f32x4*)ph, *(const f32x4*)(ph + 4));
      const float* px = wxf + (size_t)(h0 + tile * 16 + lr) * I_ + kc * 32 + g * 8;
      xB[tile * 8 + kc] = cvt8(*(const f32x4*)px, *(const f32x4*)(px + 4));
    }
  }
  const float bias0 = bias_g[h0 + lr];
  const float bias1 = bias_g[h0 + 16 + lr];
  if (tid < 128) ((f16x2*)hb[0])[tid] = f16x2{(_Float16)0.f, (_Float16)0.f};

  int cur = 0;
  for (int t0 = 0; t0 < T_; t0 += CHUNK) {
    // ---- phase 1: xp chunk from global x (read-once, coalesced), D rows = t-steps ----
#pragma unroll 1
    for (int tt = 0; tt < CHUNK / 16; ++tt) {
      f32x4 aE0 = {}, aO0 = {}, aE1 = {}, aO1 = {};
      const float* xrow = x + base + (size_t)(t0 + tt * 16 + lr) * I_;
#pragma unroll
      for (int kc = 0; kc < 8; kc += 2) {
        const f32x4* p0 = (const f32x4*)(xrow + kc * 32 + g * 8);
        f16x8 a0 = cvt8(p0[0], p0[1]);
        const f32x4* p1 = (const f32x4*)(xrow + (kc + 1) * 32 + g * 8);
        f16x8 a1 = cvt8(p1[0], p1[1]);
        aE0 = __builtin_amdgcn_mfma_f32_16x16x32_f16(a0, xB[kc],         aE0, 0, 0, 0);
        aE1 = __builtin_amdgcn_mfma_f32_16x16x32_f16(a0, xB[8 + kc],     aE1, 0, 0, 0);
        aO0 = __builtin_amdgcn_mfma_f32_16x16x32_f16(a1, xB[kc + 1],     aO0, 0, 0, 0);
        aO1 = __builtin_amdgcn_mfma_f32_16x16x32_f16(a1, xB[8 + kc + 1], aO1, 0, 0, 0);
      }
      f32x4 y0 = aE0 + aO0, y1 = aE1 + aO1;
#pragma unroll
      for (int r = 0; r < 4; ++r) {
        xps[tt * 16 + g * 4 + r][h0 + lr]      = y0[r] + bias0;
        xps[tt * 16 + g * 4 + r][h0 + 16 + lr] = y1[r] + bias1;
      }
    }
    __syncthreads();                                  // xps ready; drains x loads once/chunk

    // ---- phase 2: 64 recurrence steps, LDS only ----
#pragma unroll 1
    for (int s = 0; s < CHUNK; ++s) {
      const float xp0 = xps[s][h0 + lr];
      const float xp1 = xps[s][h0 + 16 + lr];
      f32x4 aE0 = {}, aO0 = {}, aE1 = {}, aO1 = {};
      const f16x8* hp = (const f16x8*)hb[cur];
#pragma unroll
      for (int kc = 0; kc < 8; kc += 2) {
        f16x8 hv0 = hp[kc * 4 + g];                   // broadcast: 4 distinct addrs/wave
        f16x8 hv1 = hp[(kc + 1) * 4 + g];
        aE0 = __builtin_amdgcn_mfma_f32_16x16x32_f16(hv0, wB[kc],         aE0, 0, 0, 0);
        aE1 = __builtin_amdgcn_mfma_f32_16x16x32_f16(hv0, wB[8 + kc],     aE1, 0, 0, 0);
        aO0 = __builtin_amdgcn_mfma_f32_16x16x32_f16(hv1, wB[kc + 1],     aO0, 0, 0, 0);
        aO1 = __builtin_amdgcn_mfma_f32_16x16x32_f16(hv1, wB[8 + kc + 1], aO1, 0, 0, 0);
      }
      // every D row equals y (broadcast A) -> reg 0 holds y[h0(+16)+lr] in all lanes
      float y0 = aE0[0] + aO0[0] + xp0;
      float y1 = aE1[0] + aO1[0] + xp1;
      float e0 = __expf(2.f * y0);
      float hv0 = 1.f - 2.f * __builtin_amdgcn_rcpf(1.f + e0);   // tanh
      float e1 = __expf(2.f * y1);
      float hv1 = 1.f - 2.f * __builtin_amdgcn_rcpf(1.f + e1);
      if (l < 16) {                                   // lanes 0-15 carry the 32 outputs
        outs[s][h0 + lr]      = hv0;
        outs[s][h0 + 16 + lr] = hv1;
        _Float16* hn = hb[cur ^ 1];
        hn[h0 + lr]      = (_Float16)hv0;
        hn[h0 + 16 + lr] = (_Float16)hv1;
      }
      __syncthreads();                                // LDS-only drain (fast)
      cur ^= 1;
    }

    // ---- phase 3: bulk flush outs -> global ----
    {
      const f32x4* src = (const f32x4*)outs;
      f32x4* dst = (f32x4*)(io + base + (size_t)t0 * H_);
#pragma unroll
      for (int i = 0; i < (CHUNK * H_ / 4) / 512; ++i)
        dst[i * 512 + tid] = src[i * 512 + tid];
    }
    __syncthreads();                                  // outs free before next chunk reuses
  }
}

extern "C" void kernel_launch(void* const* d_in, const int* in_sizes, int n_in,
                              void* d_out, int out_size, void* d_ws, size_t ws_size,
                              hipStream_t stream) {
  const float* x  = (const float*)d_in[0];
  const float* wx = (const float*)d_in[1];
  const float* wh = (const float*)d_in[2];
  const float* b  = (const float*)d_in[3];
  float* out = (float*)d_out;
  (void)d_ws; (void)ws_size;
  rnn_fused<<<B_, 512, 0, stream>>>(x, wx, wh, b, out);
}